// Round 1
// baseline (180.653 us; speedup 1.0000x reference)
//
#include <hip/hip_runtime.h>

#define B_SZ 8
#define C_IN 64
#define N_PT 4096
#define BN_TOT 32768          // B*N
#define KNB 20                // neighbors
#define KSZ 20                // kernel_size
#define C_OUT 64
#define BN_EPS 1e-5f

// ---------------------------------------------------------------------------
// K0: build shuffled+transposed conv weight w2t[c][o] = conv_w[o][smap(c)]
//     where smap(c) = (c%16)*4 + c/16  (the GROUP=4 channel shuffle),
//     and zero the BN sum/sumsq accumulators (ws is poisoned 0xAA each call).
// ---------------------------------------------------------------------------
__global__ void k0_prep(const float* __restrict__ conv_w,
                        float* __restrict__ w2t,
                        float* __restrict__ sums /* 128 floats */) {
    int t = threadIdx.x;
    for (int i = t; i < C_IN * C_OUT; i += 256) {
        int c = i >> 6, o = i & 63;
        int cs = ((c & 15) << 2) | (c >> 4);
        w2t[c * 64 + o] = conv_w[o * 64 + cs];
    }
    if (t < 128) sums[t] = 0.f;
}

// ---------------------------------------------------------------------------
// K1: G[m][o] = sum_c w2t[c][o] * feature[b][c][n],  m = b*N + n
//     512 blocks: (b, 64-point tile). 256 threads = 4 waves.
//     Wave w computes o in [w*16, w*16+16) for all 64 points (lane = point).
// ---------------------------------------------------------------------------
__global__ __launch_bounds__(256) void k1_gemm(const float* __restrict__ feat,
                                               const float* __restrict__ w2t,
                                               float* __restrict__ G) {
    __shared__ float fl[C_IN * 64];          // [c][p], 16 KiB
    const int b  = blockIdx.x >> 6;
    const int n0 = (blockIdx.x & 63) << 6;
    const int t  = threadIdx.x;

    // stage feature tile: 64 channels x 64 points, float4-coalesced
    const float4* fsrc = reinterpret_cast<const float4*>(
        feat + (size_t)b * C_IN * N_PT + n0);
    float4* fl4 = reinterpret_cast<float4*>(fl);
#pragma unroll
    for (int j = 0; j < 4; ++j) {
        int idx = j * 256 + t;               // 0..1023 float4 slots
        int c = idx >> 4, p4 = idx & 15;
        fl4[idx] = fsrc[c * (N_PT / 4) + p4];
    }
    __syncthreads();

    const int lane = t & 63;
    const int ob = __builtin_amdgcn_readfirstlane((t >> 6) << 4); // 0,16,32,48

    float acc[16];
#pragma unroll
    for (int j = 0; j < 16; ++j) acc[j] = 0.f;

#pragma unroll 8
    for (int c = 0; c < C_IN; ++c) {
        float fc = fl[c * 64 + lane];                    // stride-1, no conflict
        const float* wrow = w2t + c * 64 + ob;           // wave-uniform -> s_load
#pragma unroll
        for (int j = 0; j < 16; ++j) acc[j] += fc * wrow[j];
    }

    size_t m = (size_t)b * N_PT + n0 + lane;
    float4* gdst = reinterpret_cast<float4*>(G + m * 64 + ob);
#pragma unroll
    for (int j = 0; j < 4; ++j)
        gdst[j] = make_float4(acc[4 * j], acc[4 * j + 1],
                              acc[4 * j + 2], acc[4 * j + 3]);
}

// ---------------------------------------------------------------------------
// K2: per point n: out[o,s] = sum_k G[idx[n,k]][o] * P[n][k][s]
//     omax[n][o] = max_s + conv_b[o];  accumulate BN sum/sumsq.
//     Wave-per-point: lane = o. idx & P reads are wave-uniform -> scalar loads.
//     1024 blocks x 4 waves x 8 points.
// ---------------------------------------------------------------------------
__global__ __launch_bounds__(256) void k2_main(const int* __restrict__ nidx,
                                               const float* __restrict__ P,
                                               const float* __restrict__ G,
                                               const float* __restrict__ conv_b,
                                               float* __restrict__ omax,
                                               float* __restrict__ sums) {
    const int t = threadIdx.x;
    const int lane = t & 63;
    const int wid = t >> 6;
    const int gw = blockIdx.x * 4 + wid;     // 0..4095
    const float cb = conv_b[lane];
    float ls = 0.f, ls2 = 0.f;

    for (int i = 0; i < 8; ++i) {
        const int n = __builtin_amdgcn_readfirstlane(gw * 8 + i);

        const int* ip = nidx + (size_t)n * KNB;
        float g[KNB];
#pragma unroll
        for (int k = 0; k < KNB; ++k) {
            int m = ip[k];                               // uniform -> s_load
            g[k] = G[(size_t)m * 64 + lane];             // coalesced 256B row
        }

        float acc[KSZ];
#pragma unroll
        for (int s = 0; s < KSZ; ++s) acc[s] = 0.f;

        const float* pp = P + (size_t)n * (KNB * KSZ);   // uniform -> s_load
#pragma unroll
        for (int k = 0; k < KNB; ++k) {
#pragma unroll
            for (int s = 0; s < KSZ; ++s)
                acc[s] += g[k] * pp[k * KSZ + s];
        }

        float mx = acc[0];
#pragma unroll
        for (int s = 1; s < KSZ; ++s) mx = fmaxf(mx, acc[s]);
        mx += cb;
        omax[(size_t)n * 64 + lane] = mx;                // coalesced
        ls += mx;
        ls2 += mx * mx;
    }

    // block-level BN partial reduction, then 2 atomics per lane
    __shared__ float r1[4][64], r2[4][64];
    r1[wid][lane] = ls;
    r2[wid][lane] = ls2;
    __syncthreads();
    if (wid == 0) {
        float a = r1[0][lane] + r1[1][lane] + r1[2][lane] + r1[3][lane];
        float c2 = r2[0][lane] + r2[1][lane] + r2[2][lane] + r2[3][lane];
        atomicAdd(&sums[lane], a);
        atomicAdd(&sums[64 + lane], c2);
    }
}

// ---------------------------------------------------------------------------
// K3: finalize BN stats -> scale/shift per channel (64 threads)
// ---------------------------------------------------------------------------
__global__ void k3_stats(const float* __restrict__ sums,
                         const float* __restrict__ bn_w,
                         const float* __restrict__ bn_b,
                         float* __restrict__ ss) {
    int o = threadIdx.x;
    const float inv = 1.f / (float)BN_TOT;
    float mean = sums[o] * inv;
    float var = sums[64 + o] * inv - mean * mean;
    float rstd = rsqrtf(var + BN_EPS);
    float sc = rstd * bn_w[o];
    ss[o] = sc;
    ss[64 + o] = bn_b[o] - mean * sc;
}

// ---------------------------------------------------------------------------
// K4: apply BN + transpose [BN,64] -> [B,64,N]
//     512 blocks: (b, 64-point tile); wave w handles channels [w*16, w*16+16).
// ---------------------------------------------------------------------------
__global__ __launch_bounds__(256) void k4_apply(const float* __restrict__ omax,
                                                const float* __restrict__ ss,
                                                float* __restrict__ out) {
    const int b  = blockIdx.x >> 6;
    const int n0 = (blockIdx.x & 63) << 6;
    const int t  = threadIdx.x;
    const int nl = t & 63;
    const int ob = __builtin_amdgcn_readfirstlane((t >> 6) << 4);

    const size_t m = (size_t)b * N_PT + n0 + nl;
    const float4* src = reinterpret_cast<const float4*>(omax + m * 64 + ob);
    float v[16];
#pragma unroll
    for (int j = 0; j < 4; ++j) {
        float4 x = src[j];
        v[4 * j] = x.x; v[4 * j + 1] = x.y; v[4 * j + 2] = x.z; v[4 * j + 3] = x.w;
    }
#pragma unroll
    for (int j = 0; j < 16; ++j) {
        int o = ob + j;
        float sc = ss[o];            // uniform -> s_load
        float sh = ss[64 + o];
        out[(size_t)b * C_OUT * N_PT + (size_t)o * N_PT + n0 + nl] =
            v[j] * sc + sh;          // coalesced 256B store
    }
}

// ---------------------------------------------------------------------------
extern "C" void kernel_launch(void* const* d_in, const int* in_sizes, int n_in,
                              void* d_out, int out_size, void* d_ws, size_t ws_size,
                              hipStream_t stream) {
    const float* feature = (const float*)d_in[0];
    const int*   nidx    = (const int*)d_in[1];
    const float* perm    = (const float*)d_in[2];
    const float* conv_w  = (const float*)d_in[3];
    const float* conv_b  = (const float*)d_in[4];
    const float* bn_w    = (const float*)d_in[5];
    const float* bn_b    = (const float*)d_in[6];
    float* out = (float*)d_out;

    char* ws = (char*)d_ws;
    float* G    = (float*)ws;                                   // 8 MiB
    float* OM   = (float*)(ws + (size_t)8 * 1024 * 1024);       // 8 MiB
    float* W2T  = (float*)(ws + (size_t)16 * 1024 * 1024);      // 16 KiB
    float* SUMS = W2T + 4096;                                   // 128 floats
    float* SS   = SUMS + 128;                                   // 128 floats

    k0_prep<<<1, 256, 0, stream>>>(conv_w, W2T, SUMS);
    k1_gemm<<<512, 256, 0, stream>>>(feature, W2T, G);
    k2_main<<<1024, 256, 0, stream>>>(nidx, perm, G, conv_b, OM, SUMS);
    k3_stats<<<1, 64, 0, stream>>>(SUMS, bn_w, bn_b, SS);
    k4_apply<<<512, 256, 0, stream>>>(OM, SS, out);
}